// Round 7
// baseline (453.547 us; speedup 1.0000x reference)
//
#include <hip/hip_runtime.h>

#define DIN 256
#define DH  128
#define DOUT 64
#define BSH  7          // bucket = 128 nodes
#define BNODES 128
#define MAXBUK 400      // >= ceil(N/128); N=50000 -> 391
#define NBLK 512        // histogram/scatter grid

typedef unsigned int  u32;
typedef unsigned short u16;
typedef __attribute__((ext_vector_type(8))) short bf16x8;
typedef __attribute__((ext_vector_type(4))) float f32x4;

__device__ inline u16 f2bf(float f) {            // fp32 -> bf16 round-nearest-even
  u32 u = __float_as_uint(f);
  u32 r = u + 0x7FFF + ((u >> 16) & 1);
  return (u16)(r >> 16);
}
__device__ inline float bf2f_lo(u32 packed) { return __uint_as_float(packed << 16); }
__device__ inline float bf2f_hi(u32 packed) { return __uint_as_float(packed & 0xFFFF0000u); }

// ---------- radix-style CSR construction (no global atomics) ----------

__global__ __launch_bounds__(256) void hist_kernel(const int* __restrict__ dst,
    int* __restrict__ counts, int E, int nbuk) {
  __shared__ int h[MAXBUK];
  int tid = threadIdx.x, b = blockIdx.x;
  for (int i = tid; i < nbuk; i += 256) h[i] = 0;
  __syncthreads();
  int ech = (E + NBLK - 1) / NBLK;
  int e0 = b * ech, e1 = min(E, e0 + ech);
  for (int e = e0 + tid; e < e1; e += 256)
    atomicAdd(&h[dst[e] >> BSH], 1);
  __syncthreads();
  for (int i = tid; i < nbuk; i += 256) counts[(size_t)i * NBLK + b] = h[i];
}

__global__ __launch_bounds__(256) void col_scan(int* __restrict__ counts,
    int* __restrict__ colsum, int nbuk) {
  __shared__ int sm[256];
  __shared__ int carry;
  int buk = blockIdx.x, t = threadIdx.x;
  if (t == 0) carry = 0;
  __syncthreads();
  int* row = counts + (size_t)buk * NBLK;
  for (int base = 0; base < NBLK; base += 256) {
    int v = row[base + t];
    sm[t] = v;
    __syncthreads();
    for (int d = 1; d < 256; d <<= 1) {
      int a = (t >= d) ? sm[t - d] : 0;
      __syncthreads();
      sm[t] += a;
      __syncthreads();
    }
    int excl = sm[t] - v + carry;
    row[base + t] = excl;
    __syncthreads();
    if (t == 255) carry = excl + v;
    __syncthreads();
  }
  if (t == 0) colsum[buk] = carry;
}

__global__ __launch_bounds__(256) void scan_block(int* partial, int* total_out, int nb, int n) {
  __shared__ int sm[256];
  __shared__ int carry;
  int t = threadIdx.x;
  if (t == 0) carry = 0;
  __syncthreads();
  for (int base = 0; base < nb; base += 256) {
    int g = base + t;
    int v = (g < nb) ? partial[g] : 0;
    sm[t] = v;
    __syncthreads();
    for (int d = 1; d < 256; d <<= 1) {
      int add = (t >= d) ? sm[t - d] : 0;
      __syncthreads();
      sm[t] += add;
      __syncthreads();
    }
    int excl = sm[t] - v + carry;
    if (g < nb) partial[g] = excl;
    __syncthreads();
    if (t == 255) carry = excl + v;
    __syncthreads();
  }
  if (t == 0) total_out[n] = carry;
}

__global__ __launch_bounds__(256) void scatter_kernel(const int* __restrict__ src,
    const int* __restrict__ dst, const int* __restrict__ counts,
    const int* __restrict__ bb, u32* __restrict__ ebuf, int E, int nbuk) {
  __shared__ int cur[MAXBUK];
  int tid = threadIdx.x, b = blockIdx.x;
  for (int i = tid; i < nbuk; i += 256)
    cur[i] = bb[i] + counts[(size_t)i * NBLK + b];
  __syncthreads();
  int ech = (E + NBLK - 1) / NBLK;
  int e0 = b * ech, e1 = min(E, e0 + ech);
  for (int e = e0 + tid; e < e1; e += 256) {
    int d = dst[e];
    int r = atomicAdd(&cur[d >> BSH], 1);
    ebuf[r] = (u32)src[e] | ((u32)(d & (BNODES - 1)) << 16);   // N < 65536
  }
}

__global__ __launch_bounds__(256) void bucket_node_count(const u32* __restrict__ ebuf,
    const int* __restrict__ bb, int* __restrict__ cnt, int N) {
  __shared__ int c[BNODES];
  int b = blockIdx.x, tid = threadIdx.x;
  if (tid < BNODES) c[tid] = 0;
  __syncthreads();
  int e0 = bb[b], e1 = bb[b + 1];
  for (int e = e0 + tid; e < e1; e += 256)
    atomicAdd(&c[ebuf[e] >> 16], 1);
  __syncthreads();
  int node = b * BNODES + tid;
  if (tid < BNODES && node < N) cnt[node] = c[tid];
}

__global__ __launch_bounds__(256) void reduce_chunks(const int* __restrict__ cnt,
                                                     int* __restrict__ partial, int n) {
  int t = threadIdx.x;
  int g = blockIdx.x * 256 + t;
  int v = (g < n) ? cnt[g] : 0;
  #pragma unroll
  for (int o = 32; o > 0; o >>= 1) v += __shfl_down(v, o, 64);
  __shared__ int sm[4];
  if ((t & 63) == 0) sm[t >> 6] = v;
  __syncthreads();
  if (t == 0) partial[blockIdx.x] = sm[0] + sm[1] + sm[2] + sm[3];
}

__global__ __launch_bounds__(256) void scan_chunks(const int* __restrict__ cnt,
    const int* __restrict__ chunkoff, int* __restrict__ rowptr,
    float* __restrict__ dinv, int n) {
  __shared__ int sm[256];
  int t = threadIdx.x, g = blockIdx.x * 256 + t;
  int v = (g < n) ? cnt[g] : 0;
  sm[t] = v;
  __syncthreads();
  for (int d = 1; d < 256; d <<= 1) {
    int add = (t >= d) ? sm[t - d] : 0;
    __syncthreads();
    sm[t] += add;
    __syncthreads();
  }
  if (g < n) {
    rowptr[g] = sm[t] - v + chunkoff[blockIdx.x];
    dinv[g] = rsqrtf((float)(v + 1));       // +1 self-loop
  }
}

__global__ __launch_bounds__(256) void bucket_fill(const u32* __restrict__ ebuf,
    const int* __restrict__ bb, const int* __restrict__ rowptr, int* __restrict__ csr) {
  __shared__ int c[BNODES];
  int b = blockIdx.x, tid = threadIdx.x;
  if (tid < BNODES) c[tid] = 0;
  __syncthreads();
  int e0 = bb[b], e1 = bb[b + 1];
  for (int e = e0 + tid; e < e1; e += 256) {
    u32 p = ebuf[e];
    int nl = p >> 16;
    int r = atomicAdd(&c[nl], 1);
    csr[rowptr[b * BNODES + nl] + r] = (int)(p & 0xFFFFu);
  }
}

// ---------- W1 -> bf16 transposed [DH][DIN] ----------

__global__ __launch_bounds__(256) void w1_to_bf16T(const float* __restrict__ W1,
                                                   u16* __restrict__ w1t) {
  int t = blockIdx.x * 256 + threadIdx.x;
  int n = t >> 8, k = t & 255;
  w1t[t] = f2bf(W1[k * DH + n]);
}

// ---------- GEMM1: bf16 MFMA, BM=64 BN=128 BK=64, epilogue dinv*bf16 ----------

__global__ __launch_bounds__(256) void gemm1_mfma(const float* __restrict__ x,
    const u16* __restrict__ w1t, const float* __restrict__ dinv,
    u16* __restrict__ h1, int M) {
  __shared__ u16 As[64][72];
  __shared__ u16 Bs[128][72];
  const int tid = threadIdx.x;
  const int lane = tid & 63, w = tid >> 6;
  const int row16 = lane & 15, quad = lane >> 4;
  const int rowBase = blockIdx.x * 64;
  f32x4 acc[8];
  #pragma unroll
  for (int nt = 0; nt < 8; ++nt) acc[nt] = (f32x4)(0.f);

  for (int kt = 0; kt < DIN; kt += 64) {
    {
      int r = tid >> 2, kq = tid & 3;
      int grow = rowBase + r;
      #pragma unroll
      for (int i = 0; i < 4; ++i) {
        float4 v = make_float4(0.f, 0.f, 0.f, 0.f);
        if (grow < M) v = *(const float4*)&x[(size_t)grow * DIN + kt + kq * 16 + i * 4];
        u32 lo = (u32)f2bf(v.x) | ((u32)f2bf(v.y) << 16);
        u32 hi = (u32)f2bf(v.z) | ((u32)f2bf(v.w) << 16);
        *(uint2*)&As[r][kq * 16 + i * 4] = make_uint2(lo, hi);
      }
    }
    {
      int n = tid >> 1, half = tid & 1;
      const uint4* s = (const uint4*)&w1t[n * DIN + kt + half * 32];
      uint4* d = (uint4*)&Bs[n][half * 32];
      d[0] = s[0]; d[1] = s[1]; d[2] = s[2]; d[3] = s[3];
    }
    __syncthreads();
    #pragma unroll
    for (int ks = 0; ks < 64; ks += 32) {
      bf16x8 a = *(bf16x8*)&As[w * 16 + row16][ks + quad * 8];
      #pragma unroll
      for (int nt = 0; nt < 8; ++nt) {
        bf16x8 b = *(bf16x8*)&Bs[nt * 16 + row16][ks + quad * 8];
        acc[nt] = __builtin_amdgcn_mfma_f32_16x16x32_bf16(a, b, acc[nt], 0, 0, 0);
      }
    }
    __syncthreads();
  }
  #pragma unroll
  for (int reg = 0; reg < 4; ++reg) {
    int row = rowBase + w * 16 + quad * 4 + reg;
    if (row < M) {
      float s = dinv[row];
      #pragma unroll
      for (int nt = 0; nt < 8; ++nt)
        h1[(size_t)row * DH + nt * 16 + row16] = f2bf(acc[nt][reg] * s);
    }
  }
}

// ---------- GEMM2 (fp32 vector), bf16 output ----------

template<int BN, int TN>
__global__ __launch_bounds__(256) void gemm_tile(const float* __restrict__ A,
    const float* __restrict__ W, const float* __restrict__ dinv,
    u16* __restrict__ C, int M, int K) {
  const int tid = threadIdx.x;
  const int tx = tid & 31;
  const int ty = tid >> 5;
  const int rowBase = blockIdx.x * 64;
  __shared__ float xs[64][16];
  __shared__ float wsm[16][BN];
  float acc[8][TN];
  #pragma unroll
  for (int r = 0; r < 8; ++r)
    #pragma unroll
    for (int j = 0; j < TN; ++j) acc[r][j] = 0.f;

  for (int kt = 0; kt < K; kt += 16) {
    {
      int r = tid >> 2, kq = tid & 3;
      int grow = rowBase + r;
      float4 v = make_float4(0.f, 0.f, 0.f, 0.f);
      if (grow < M) v = *(const float4*)&A[(size_t)grow * K + kt + kq * 4];
      *(float4*)&xs[r][kq * 4] = v;
    }
    #pragma unroll
    for (int i = 0; i < BN / 64; ++i) {
      int idx = (tid + i * 256) * 4;
      int kk = idx / BN, c = idx % BN;
      *(float4*)&wsm[kk][c] = *(const float4*)&W[(size_t)(kt + kk) * BN + c];
    }
    __syncthreads();
    #pragma unroll
    for (int kk = 0; kk < 16; ++kk) {
      float a[8];
      #pragma unroll
      for (int r = 0; r < 8; ++r) a[r] = xs[ty * 8 + r][kk];
      float b[TN];
      if (TN == 4) {
        float4 bv = *(float4*)&wsm[kk][tx * 4];
        b[0] = bv.x; b[1] = bv.y; b[2] = bv.z; b[3] = bv.w;
      } else {
        float2 bv = *(float2*)&wsm[kk][tx * 2];
        b[0] = bv.x; b[1] = bv.y;
      }
      #pragma unroll
      for (int r = 0; r < 8; ++r)
        #pragma unroll
        for (int j = 0; j < TN; ++j) acc[r][j] = fmaf(a[r], b[j], acc[r][j]);
    }
    __syncthreads();
  }
  #pragma unroll
  for (int r = 0; r < 8; ++r) {
    int row = rowBase + ty * 8 + r;
    if (row < M) {
      float s = dinv[row];
      if (TN == 4) {
        u32 lo = (u32)f2bf(acc[r][0] * s) | ((u32)f2bf(acc[r][1] * s) << 16);
        u32 hi = (u32)f2bf(acc[r][2] * s) | ((u32)f2bf(acc[r][3] * s) << 16);
        uint2 pv; pv.x = lo; pv.y = hi;
        *(uint2*)&C[(size_t)row * BN + tx * 4] = pv;
      } else {
        u32 lo = (u32)f2bf(acc[r][0] * s) | ((u32)f2bf(acc[r][1] * s) << 16);
        *(u32*)&C[(size_t)row * BN + tx * 2] = lo;
      }
    }
  }
}

// ---------- feature-sharded pull aggregation ----------
// chunk = blockIdx & (NCH-1): with round-robin block->XCD dispatch, each XCD
// only touches one 16-feature column slice of h (1.6 MB at DH) -> L2-resident.
// Wave layout: 8 edge-groups x 8 lanes; lane = (eg, sub), u32 = 2 bf16 feats.
// shfl_xor reduction over eg; eg==0 lanes (8) write 64 B.

template<int D, int LOGC, bool RELU>
__global__ __launch_bounds__(256) void aggregate_k(const u16* __restrict__ h,
    const int* __restrict__ rowptr, const int* __restrict__ csr,
    const float* __restrict__ dinv, const float* __restrict__ bias,
    float* __restrict__ out, int n) {
  constexpr int NCH = 1 << LOGC;
  constexpr int CW  = D / NCH;      // features per chunk (16)
  constexpr int RS  = D / 2;        // h row stride in u32
  const u32* h32 = (const u32*)h;
  int lane  = threadIdx.x & 63;
  int chunk = blockIdx.x & (NCH - 1);
  int node  = (blockIdx.x >> LOGC) * 4 + (threadIdx.x >> 6);
  if (node >= n) return;
  node = __builtin_amdgcn_readfirstlane(node);
  int sub = lane & 7;               // u32 within chunk (CW/2 == 8)
  int eg  = lane >> 3;              // edge group 0..7
  int choff = chunk * (CW / 2);
  float di = dinv[node];
  float ax = 0.f, ay = 0.f;
  if (eg == 0) {                    // self-loop term, counted once
    u32 w = h32[(size_t)node * RS + choff + sub];
    ax = bf2f_lo(w); ay = bf2f_hi(w);
  }
  int p = rowptr[node], pe = rowptr[node + 1];
  for (; p + 16 <= pe; p += 16) {
    int s0 = csr[p + eg], s1 = csr[p + 8 + eg];
    u32 w0 = h32[(size_t)s0 * RS + choff + sub];
    u32 w1 = h32[(size_t)s1 * RS + choff + sub];
    ax += bf2f_lo(w0) + bf2f_lo(w1);
    ay += bf2f_hi(w0) + bf2f_hi(w1);
  }
  for (; p + 8 <= pe; p += 8) {
    int s0 = csr[p + eg];
    u32 w0 = h32[(size_t)s0 * RS + choff + sub];
    ax += bf2f_lo(w0); ay += bf2f_hi(w0);
  }
  if (p < pe) {                     // predicated tail (<8 edges)
    u32 w0 = 0;
    if (p + eg < pe) {
      int s0 = csr[p + eg];
      w0 = h32[(size_t)s0 * RS + choff + sub];
    }
    ax += bf2f_lo(w0); ay += bf2f_hi(w0);
  }
  #pragma unroll
  for (int off = 8; off < 64; off <<= 1) {
    ax += __shfl_xor(ax, off, 64);
    ay += __shfl_xor(ay, off, 64);
  }
  if (eg == 0) {
    int c0 = chunk * CW + sub * 2;
    float fx = fmaf(ax, di, bias[c0]);
    float fy = fmaf(ay, di, bias[c0 + 1]);
    if (RELU) { fx = fmaxf(fx, 0.f); fy = fmaxf(fy, 0.f); }
    *(float2*)&out[(size_t)node * D + c0] = make_float2(fx, fy);
  }
}

// ---------- launch ----------

extern "C" void kernel_launch(void* const* d_in, const int* in_sizes, int n_in,
                              void* d_out, int out_size, void* d_ws, size_t ws_size,
                              hipStream_t stream) {
  const float* x  = (const float*)d_in[0];
  const int*   ei = (const int*)d_in[1];
  const float* W1 = (const float*)d_in[2];
  const float* b1 = (const float*)d_in[3];
  const float* W2 = (const float*)d_in[4];
  const float* b2 = (const float*)d_in[5];
  float* out = (float*)d_out;

  const int N = in_sizes[0] / DIN;   // 50000
  const int E = in_sizes[1] / 2;     // 1600000
  const int* src = ei;
  const int* dst = ei + E;
  const int NB = (N + 255) / 256;
  const int nbuk = (N + BNODES - 1) / BNODES;   // 391 (<= MAXBUK)

  char* ws = (char*)d_ws;
  size_t o = 0;
  auto alloc = [&](size_t bytes) { size_t r = o; o += (bytes + 511) & ~(size_t)511; return r; };
  size_t colsum_o  = alloc((size_t)(nbuk + 1) * 4);
  size_t counts_o  = alloc((size_t)nbuk * NBLK * 4);
  size_t rowptr_o  = alloc((size_t)(N + 1) * 4);
  size_t partial_o = alloc((size_t)NB * 4);
  size_t dinv_o    = alloc((size_t)N * 4);
  size_t cnt_o     = alloc((size_t)N * 4);
  size_t w1t_o     = alloc((size_t)DH * DIN * 2);
  size_t csr_o     = alloc((size_t)E * 4);
  size_t h1_o      = alloc((size_t)N * DH * 2);   // bf16
  size_t g1_o      = alloc((size_t)N * DH * 4);   // fp32 (GEMM2 input)
  size_t h2_o      = h1_o;   // h1 dead after aggregate1 -> reuse (bf16)
  size_t ebuf_o    = g1_o;   // ebuf dead before aggregate1 writes g1

  int*   colsum  = (int*)(ws + colsum_o);   // becomes bb after scan_block
  int*   counts  = (int*)(ws + counts_o);
  int*   rowptr  = (int*)(ws + rowptr_o);
  int*   partial = (int*)(ws + partial_o);
  float* dinv    = (float*)(ws + dinv_o);
  int*   cnt     = (int*)(ws + cnt_o);
  u16*   w1t     = (u16*)(ws + w1t_o);
  int*   csr     = (int*)(ws + csr_o);
  u16*   h1      = (u16*)(ws + h1_o);
  float* g1      = (float*)(ws + g1_o);
  u16*   h2      = (u16*)(ws + h2_o);
  u32*   ebuf    = (u32*)(ws + ebuf_o);

  w1_to_bf16T<<<(DH * DIN) / 256, 256, 0, stream>>>(W1, w1t);
  hist_kernel<<<NBLK, 256, 0, stream>>>(dst, counts, E, nbuk);
  col_scan<<<nbuk, 256, 0, stream>>>(counts, colsum, nbuk);
  scan_block<<<1, 256, 0, stream>>>(colsum, colsum, nbuk, nbuk);  // colsum -> bb, bb[nbuk]=E
  scatter_kernel<<<NBLK, 256, 0, stream>>>(src, dst, counts, colsum, ebuf, E, nbuk);
  bucket_node_count<<<nbuk, 256, 0, stream>>>(ebuf, colsum, cnt, N);
  reduce_chunks<<<NB, 256, 0, stream>>>(cnt, partial, N);
  scan_block<<<1, 256, 0, stream>>>(partial, rowptr, NB, N);
  scan_chunks<<<NB, 256, 0, stream>>>(cnt, partial, rowptr, dinv, N);
  bucket_fill<<<nbuk, 256, 0, stream>>>(ebuf, colsum, rowptr, csr);

  gemm1_mfma<<<(N + 63) / 64, 256, 0, stream>>>(x, w1t, dinv, h1, N);
  aggregate_k<DH, 3, true><<<((N + 3) / 4) * 8, 256, 0, stream>>>(h1, rowptr, csr, dinv, b1, g1, N);
  gemm_tile<DOUT, 2><<<(N + 63) / 64, 256, 0, stream>>>(g1, W2, dinv, h2, N, DH);
  aggregate_k<DOUT, 2, false><<<((N + 3) / 4) * 4, 256, 0, stream>>>(h2, rowptr, csr, dinv, b2, out, N);
}

// Round 8
// 248.122 us; speedup vs baseline: 1.8279x; 1.8279x over previous
//
#include <hip/hip_runtime.h>

#define DIN 256
#define DH  128
#define DOUT 64
#define BSH  7          // bucket = 128 nodes
#define BNODES 128
#define MAXBUK 400      // >= ceil(N/128); N=50000 -> 391
#define NBLK 512        // histogram/scatter grid

typedef unsigned int  u32;
typedef unsigned short u16;
typedef __attribute__((ext_vector_type(8))) short bf16x8;
typedef __attribute__((ext_vector_type(4))) float f32x4;

__device__ inline u16 f2bf(float f) {            // fp32 -> bf16 round-nearest-even
  u32 u = __float_as_uint(f);
  u32 r = u + 0x7FFF + ((u >> 16) & 1);
  return (u16)(r >> 16);
}
__device__ inline float bf2f_lo(u32 packed) { return __uint_as_float(packed << 16); }
__device__ inline float bf2f_hi(u32 packed) { return __uint_as_float(packed & 0xFFFF0000u); }

// ---------- radix-style CSR construction (no global atomics) ----------

__global__ __launch_bounds__(256) void hist_kernel(const int* __restrict__ dst,
    int* __restrict__ counts, int E, int nbuk) {
  __shared__ int h[MAXBUK];
  int tid = threadIdx.x, b = blockIdx.x;
  for (int i = tid; i < nbuk; i += 256) h[i] = 0;
  __syncthreads();
  int ech = (E + NBLK - 1) / NBLK;
  int e0 = b * ech, e1 = min(E, e0 + ech);
  for (int e = e0 + tid; e < e1; e += 256)
    atomicAdd(&h[dst[e] >> BSH], 1);
  __syncthreads();
  for (int i = tid; i < nbuk; i += 256) counts[(size_t)i * NBLK + b] = h[i];
}

__global__ __launch_bounds__(256) void col_scan(int* __restrict__ counts,
    int* __restrict__ colsum, int nbuk) {
  __shared__ int sm[256];
  __shared__ int carry;
  int buk = blockIdx.x, t = threadIdx.x;
  if (t == 0) carry = 0;
  __syncthreads();
  int* row = counts + (size_t)buk * NBLK;
  for (int base = 0; base < NBLK; base += 256) {
    int v = row[base + t];
    sm[t] = v;
    __syncthreads();
    for (int d = 1; d < 256; d <<= 1) {
      int a = (t >= d) ? sm[t - d] : 0;
      __syncthreads();
      sm[t] += a;
      __syncthreads();
    }
    int excl = sm[t] - v + carry;
    row[base + t] = excl;
    __syncthreads();
    if (t == 255) carry = excl + v;
    __syncthreads();
  }
  if (t == 0) colsum[buk] = carry;
}

__global__ __launch_bounds__(256) void scan_block(int* partial, int* total_out, int nb, int n) {
  __shared__ int sm[256];
  __shared__ int carry;
  int t = threadIdx.x;
  if (t == 0) carry = 0;
  __syncthreads();
  for (int base = 0; base < nb; base += 256) {
    int g = base + t;
    int v = (g < nb) ? partial[g] : 0;
    sm[t] = v;
    __syncthreads();
    for (int d = 1; d < 256; d <<= 1) {
      int add = (t >= d) ? sm[t - d] : 0;
      __syncthreads();
      sm[t] += add;
      __syncthreads();
    }
    int excl = sm[t] - v + carry;
    if (g < nb) partial[g] = excl;
    __syncthreads();
    if (t == 255) carry = excl + v;
    __syncthreads();
  }
  if (t == 0) total_out[n] = carry;
}

__global__ __launch_bounds__(256) void scatter_kernel(const int* __restrict__ src,
    const int* __restrict__ dst, const int* __restrict__ counts,
    const int* __restrict__ bb, u32* __restrict__ ebuf, int E, int nbuk) {
  __shared__ int cur[MAXBUK];
  int tid = threadIdx.x, b = blockIdx.x;
  for (int i = tid; i < nbuk; i += 256)
    cur[i] = bb[i] + counts[(size_t)i * NBLK + b];
  __syncthreads();
  int ech = (E + NBLK - 1) / NBLK;
  int e0 = b * ech, e1 = min(E, e0 + ech);
  for (int e = e0 + tid; e < e1; e += 256) {
    int d = dst[e];
    int r = atomicAdd(&cur[d >> BSH], 1);
    ebuf[r] = (u32)src[e] | ((u32)(d & (BNODES - 1)) << 16);   // N < 65536
  }
}

__global__ __launch_bounds__(256) void bucket_node_count(const u32* __restrict__ ebuf,
    const int* __restrict__ bb, int* __restrict__ cnt, int N) {
  __shared__ int c[BNODES];
  int b = blockIdx.x, tid = threadIdx.x;
  if (tid < BNODES) c[tid] = 0;
  __syncthreads();
  int e0 = bb[b], e1 = bb[b + 1];
  for (int e = e0 + tid; e < e1; e += 256)
    atomicAdd(&c[ebuf[e] >> 16], 1);
  __syncthreads();
  int node = b * BNODES + tid;
  if (tid < BNODES && node < N) cnt[node] = c[tid];
}

__global__ __launch_bounds__(256) void reduce_chunks(const int* __restrict__ cnt,
                                                     int* __restrict__ partial, int n) {
  int t = threadIdx.x;
  int g = blockIdx.x * 256 + t;
  int v = (g < n) ? cnt[g] : 0;
  #pragma unroll
  for (int o = 32; o > 0; o >>= 1) v += __shfl_down(v, o, 64);
  __shared__ int sm[4];
  if ((t & 63) == 0) sm[t >> 6] = v;
  __syncthreads();
  if (t == 0) partial[blockIdx.x] = sm[0] + sm[1] + sm[2] + sm[3];
}

__global__ __launch_bounds__(256) void scan_chunks(const int* __restrict__ cnt,
    const int* __restrict__ chunkoff, int* __restrict__ rowptr,
    float* __restrict__ dinv, int n) {
  __shared__ int sm[256];
  int t = threadIdx.x, g = blockIdx.x * 256 + t;
  int v = (g < n) ? cnt[g] : 0;
  sm[t] = v;
  __syncthreads();
  for (int d = 1; d < 256; d <<= 1) {
    int add = (t >= d) ? sm[t - d] : 0;
    __syncthreads();
    sm[t] += add;
    __syncthreads();
  }
  if (g < n) {
    rowptr[g] = sm[t] - v + chunkoff[blockIdx.x];
    dinv[g] = rsqrtf((float)(v + 1));       // +1 self-loop
  }
}

__global__ __launch_bounds__(256) void bucket_fill(const u32* __restrict__ ebuf,
    const int* __restrict__ bb, const int* __restrict__ rowptr, int* __restrict__ csr) {
  __shared__ int c[BNODES];
  int b = blockIdx.x, tid = threadIdx.x;
  if (tid < BNODES) c[tid] = 0;
  __syncthreads();
  int e0 = bb[b], e1 = bb[b + 1];
  for (int e = e0 + tid; e < e1; e += 256) {
    u32 p = ebuf[e];
    int nl = p >> 16;
    int r = atomicAdd(&c[nl], 1);
    csr[rowptr[b * BNODES + nl] + r] = (int)(p & 0xFFFFu);
  }
}

// ---------- W1,W2 -> bf16 transposed (one-shot, tiny) ----------

__global__ __launch_bounds__(256) void w_prep(const float* __restrict__ W1,
    const float* __restrict__ W2, u16* __restrict__ w1t, u16* __restrict__ w2t) {
  int t = blockIdx.x * 256 + threadIdx.x;     // 40960 threads
  if (t < DH * DIN) {
    int n = t >> 8, k = t & 255;
    w1t[t] = f2bf(W1[k * DH + n]);            // w1t[n*256+k]
  } else {
    int t2 = t - DH * DIN;
    int n = t2 >> 7, k = t2 & 127;
    w2t[t2] = f2bf(W2[k * DOUT + n]);         // w2t[n*128+k]
  }
}

// ---------- GEMM1: bf16 MFMA, BM=64 BN=128 BK=64, epilogue dinv*bf16 ----------

__global__ __launch_bounds__(256) void gemm1_mfma(const float* __restrict__ x,
    const u16* __restrict__ w1t, const float* __restrict__ dinv,
    u16* __restrict__ h1, int M) {
  __shared__ u16 As[64][72];
  __shared__ u16 Bs[128][72];
  const int tid = threadIdx.x;
  const int lane = tid & 63, w = tid >> 6;
  const int row16 = lane & 15, quad = lane >> 4;
  const int rowBase = blockIdx.x * 64;
  f32x4 acc[8];
  #pragma unroll
  for (int nt = 0; nt < 8; ++nt) acc[nt] = (f32x4)(0.f);

  for (int kt = 0; kt < DIN; kt += 64) {
    {
      int r = tid >> 2, kq = tid & 3;
      int grow = rowBase + r;
      #pragma unroll
      for (int i = 0; i < 4; ++i) {
        float4 v = make_float4(0.f, 0.f, 0.f, 0.f);
        if (grow < M) v = *(const float4*)&x[(size_t)grow * DIN + kt + kq * 16 + i * 4];
        u32 lo = (u32)f2bf(v.x) | ((u32)f2bf(v.y) << 16);
        u32 hi = (u32)f2bf(v.z) | ((u32)f2bf(v.w) << 16);
        *(uint2*)&As[r][kq * 16 + i * 4] = make_uint2(lo, hi);
      }
    }
    {
      int n = tid >> 1, half = tid & 1;
      const uint4* s = (const uint4*)&w1t[n * DIN + kt + half * 32];
      uint4* d = (uint4*)&Bs[n][half * 32];
      d[0] = s[0]; d[1] = s[1]; d[2] = s[2]; d[3] = s[3];
    }
    __syncthreads();
    #pragma unroll
    for (int ks = 0; ks < 64; ks += 32) {
      bf16x8 a = *(bf16x8*)&As[w * 16 + row16][ks + quad * 8];
      #pragma unroll
      for (int nt = 0; nt < 8; ++nt) {
        bf16x8 b = *(bf16x8*)&Bs[nt * 16 + row16][ks + quad * 8];
        acc[nt] = __builtin_amdgcn_mfma_f32_16x16x32_bf16(a, b, acc[nt], 0, 0, 0);
      }
    }
    __syncthreads();
  }
  #pragma unroll
  for (int reg = 0; reg < 4; ++reg) {
    int row = rowBase + w * 16 + quad * 4 + reg;
    if (row < M) {
      float s = dinv[row];
      #pragma unroll
      for (int nt = 0; nt < 8; ++nt)
        h1[(size_t)row * DH + nt * 16 + row16] = f2bf(acc[nt][reg] * s);
    }
  }
}

// ---------- GEMM2: bf16 MFMA, BM=64 BN=64, K=128 staged once ----------
// rows padded to 136 bf16 (272 B, 16B-aligned, 4-bank rotation/row)

__global__ __launch_bounds__(256) void gemm2_mfma(const u16* __restrict__ g1,
    const u16* __restrict__ w2t, const float* __restrict__ dinv,
    u16* __restrict__ h2, int M) {
  __shared__ u16 As[64][136];
  __shared__ u16 Bs[64][136];
  const int tid = threadIdx.x;
  const int lane = tid & 63, w = tid >> 6;
  const int row16 = lane & 15, quad = lane >> 4;
  const int rowBase = blockIdx.x * 64;
  f32x4 acc[4];
  #pragma unroll
  for (int nt = 0; nt < 4; ++nt) acc[nt] = (f32x4)(0.f);

  #pragma unroll
  for (int i = 0; i < 4; ++i) {        // A: 64 rows x 128 bf16 (1024 uint4)
    int flat = i * 256 + tid;
    int r = flat >> 4, c = flat & 15;
    int grow = rowBase + r;
    uint4 v = make_uint4(0, 0, 0, 0);
    if (grow < M) v = *(const uint4*)&g1[(size_t)grow * DH + c * 8];
    *(uint4*)&As[r][c * 8] = v;
  }
  #pragma unroll
  for (int i = 0; i < 4; ++i) {        // B: w2t 64 x 128 bf16
    int flat = i * 256 + tid;
    int r = flat >> 4, c = flat & 15;
    *(uint4*)&Bs[r][c * 8] = *(const uint4*)&w2t[r * DH + c * 8];
  }
  __syncthreads();
  #pragma unroll
  for (int ks = 0; ks < 128; ks += 32) {
    bf16x8 a = *(bf16x8*)&As[w * 16 + row16][ks + quad * 8];
    #pragma unroll
    for (int nt = 0; nt < 4; ++nt) {
      bf16x8 b = *(bf16x8*)&Bs[nt * 16 + row16][ks + quad * 8];
      acc[nt] = __builtin_amdgcn_mfma_f32_16x16x32_bf16(a, b, acc[nt], 0, 0, 0);
    }
  }
  #pragma unroll
  for (int reg = 0; reg < 4; ++reg) {
    int row = rowBase + w * 16 + quad * 4 + reg;
    if (row < M) {
      float s = dinv[row];
      #pragma unroll
      for (int nt = 0; nt < 4; ++nt)
        h2[(size_t)row * DOUT + nt * 16 + row16] = f2bf(acc[nt][reg] * s);
    }
  }
}

// ---------- pull aggregation: one wave per node, 16-deep gather, bf16 rows ----------

// layer 1: h rows 256 B; out g1 in bf16 (packed u32 store)
__global__ __launch_bounds__(256) void aggregate1(const u16* __restrict__ h,
    const int* __restrict__ rowptr, const int* __restrict__ csr,
    const float* __restrict__ dinv, const float* __restrict__ bias,
    u16* __restrict__ out, int n) {
  int lane = threadIdx.x & 63;
  int node = blockIdx.x * 4 + (threadIdx.x >> 6);
  if (node >= n) return;
  node = __builtin_amdgcn_readfirstlane(node);
  float di = dinv[node];
  int c0 = lane * 2;
  u32 w0 = *(const u32*)&h[(size_t)node * DH + c0];
  float ax = bf2f_lo(w0), ay = bf2f_hi(w0);
  int p = rowptr[node], pe = rowptr[node + 1];
  for (; p + 16 <= pe; p += 16) {
    int s[16];
    #pragma unroll
    for (int j = 0; j < 16; ++j) s[j] = csr[p + j];
    #pragma unroll
    for (int j = 0; j < 16; ++j) {
      u32 w = *(const u32*)&h[(size_t)s[j] * DH + c0];
      ax += bf2f_lo(w); ay += bf2f_hi(w);
    }
  }
  for (; p + 4 <= pe; p += 4) {
    int s[4];
    #pragma unroll
    for (int j = 0; j < 4; ++j) s[j] = csr[p + j];
    #pragma unroll
    for (int j = 0; j < 4; ++j) {
      u32 w = *(const u32*)&h[(size_t)s[j] * DH + c0];
      ax += bf2f_lo(w); ay += bf2f_hi(w);
    }
  }
  for (; p < pe; ++p) {
    u32 w = *(const u32*)&h[(size_t)csr[p] * DH + c0];
    ax += bf2f_lo(w); ay += bf2f_hi(w);
  }
  ax = fmaxf(fmaf(ax, di, bias[c0]), 0.f);
  ay = fmaxf(fmaf(ay, di, bias[c0 + 1]), 0.f);
  u32 pk = (u32)f2bf(ax) | ((u32)f2bf(ay) << 16);
  *(u32*)&out[(size_t)node * DH + c0] = pk;
}

// layer 2: h rows 128 B; out fp32 (final output)
__global__ __launch_bounds__(256) void aggregate2(const u16* __restrict__ h,
    const int* __restrict__ rowptr, const int* __restrict__ csr,
    const float* __restrict__ dinv, const float* __restrict__ bias,
    float* __restrict__ out, int n) {
  int lane = threadIdx.x & 63;
  int node = blockIdx.x * 4 + (threadIdx.x >> 6);
  if (node >= n) return;
  node = __builtin_amdgcn_readfirstlane(node);
  float di = dinv[node];
  float a = __uint_as_float((u32)h[(size_t)node * DOUT + lane] << 16);
  int p = rowptr[node], pe = rowptr[node + 1];
  for (; p + 16 <= pe; p += 16) {
    int s[16];
    #pragma unroll
    for (int j = 0; j < 16; ++j) s[j] = csr[p + j];
    #pragma unroll
    for (int j = 0; j < 16; ++j)
      a += __uint_as_float((u32)h[(size_t)s[j] * DOUT + lane] << 16);
  }
  for (; p + 4 <= pe; p += 4) {
    int s[4];
    #pragma unroll
    for (int j = 0; j < 4; ++j) s[j] = csr[p + j];
    #pragma unroll
    for (int j = 0; j < 4; ++j)
      a += __uint_as_float((u32)h[(size_t)s[j] * DOUT + lane] << 16);
  }
  for (; p < pe; ++p)
    a += __uint_as_float((u32)h[(size_t)csr[p] * DOUT + lane] << 16);
  out[(size_t)node * DOUT + lane] = fmaf(a, di, bias[lane]);
}

// ---------- launch ----------

extern "C" void kernel_launch(void* const* d_in, const int* in_sizes, int n_in,
                              void* d_out, int out_size, void* d_ws, size_t ws_size,
                              hipStream_t stream) {
  const float* x  = (const float*)d_in[0];
  const int*   ei = (const int*)d_in[1];
  const float* W1 = (const float*)d_in[2];
  const float* b1 = (const float*)d_in[3];
  const float* W2 = (const float*)d_in[4];
  const float* b2 = (const float*)d_in[5];
  float* out = (float*)d_out;

  const int N = in_sizes[0] / DIN;   // 50000
  const int E = in_sizes[1] / 2;     // 1600000
  const int* src = ei;
  const int* dst = ei + E;
  const int NB = (N + 255) / 256;
  const int nbuk = (N + BNODES - 1) / BNODES;   // 391 (<= MAXBUK)

  char* ws = (char*)d_ws;
  size_t o = 0;
  auto alloc = [&](size_t bytes) { size_t r = o; o += (bytes + 511) & ~(size_t)511; return r; };
  size_t colsum_o  = alloc((size_t)(nbuk + 1) * 4);
  size_t counts_o  = alloc((size_t)nbuk * NBLK * 4);
  size_t rowptr_o  = alloc((size_t)(N + 1) * 4);
  size_t partial_o = alloc((size_t)NB * 4);
  size_t dinv_o    = alloc((size_t)N * 4);
  size_t cnt_o     = alloc((size_t)N * 4);
  size_t w1t_o     = alloc((size_t)DH * DIN * 2);
  size_t w2t_o     = alloc((size_t)DOUT * DH * 2);
  size_t csr_o     = alloc((size_t)E * 4);
  size_t h1_o      = alloc((size_t)N * DH * 2);   // bf16
  size_t g1_o      = alloc((size_t)N * DH * 2);   // bf16 (GEMM2 input)
  size_t h2_o      = h1_o;   // h1 dead after aggregate1 -> reuse (bf16)
  size_t ebuf_o    = g1_o;   // ebuf dead before aggregate1 writes g1

  int*   colsum  = (int*)(ws + colsum_o);   // becomes bb after scan_block
  int*   counts  = (int*)(ws + counts_o);
  int*   rowptr  = (int*)(ws + rowptr_o);
  int*   partial = (int*)(ws + partial_o);
  float* dinv    = (float*)(ws + dinv_o);
  int*   cnt     = (int*)(ws + cnt_o);
  u16*   w1t     = (u16*)(ws + w1t_o);
  u16*   w2t     = (u16*)(ws + w2t_o);
  int*   csr     = (int*)(ws + csr_o);
  u16*   h1      = (u16*)(ws + h1_o);
  u16*   g1      = (u16*)(ws + g1_o);
  u16*   h2      = (u16*)(ws + h2_o);
  u32*   ebuf    = (u32*)(ws + ebuf_o);

  w_prep<<<(DH * DIN + DOUT * DH) / 256, 256, 0, stream>>>(W1, W2, w1t, w2t);
  hist_kernel<<<NBLK, 256, 0, stream>>>(dst, counts, E, nbuk);
  col_scan<<<nbuk, 256, 0, stream>>>(counts, colsum, nbuk);
  scan_block<<<1, 256, 0, stream>>>(colsum, colsum, nbuk, nbuk);  // colsum -> bb, bb[nbuk]=E
  scatter_kernel<<<NBLK, 256, 0, stream>>>(src, dst, counts, colsum, ebuf, E, nbuk);
  bucket_node_count<<<nbuk, 256, 0, stream>>>(ebuf, colsum, cnt, N);
  reduce_chunks<<<NB, 256, 0, stream>>>(cnt, partial, N);
  scan_block<<<1, 256, 0, stream>>>(partial, rowptr, NB, N);
  scan_chunks<<<NB, 256, 0, stream>>>(cnt, partial, rowptr, dinv, N);
  bucket_fill<<<nbuk, 256, 0, stream>>>(ebuf, colsum, rowptr, csr);

  gemm1_mfma<<<(N + 63) / 64, 256, 0, stream>>>(x, w1t, dinv, h1, N);
  aggregate1<<<(N + 3) / 4, 256, 0, stream>>>(h1, rowptr, csr, dinv, b1, g1, N);
  gemm2_mfma<<<(N + 63) / 64, 256, 0, stream>>>(g1, w2t, dinv, h2, N);
  aggregate2<<<(N + 3) / 4, 256, 0, stream>>>(h2, rowptr, csr, dinv, b2, out, N);
}